// Round 4
// baseline (192.452 us; speedup 1.0000x reference)
//
#include <hip/hip_runtime.h>
#include <stdint.h>

#define H 192
#define W 192
#define CIN 32
#define NOUT 32
#define NB 16
#define PADI 4

#define HT 16          // output rows per block
#define WTL 16         // output cols per block
#define RR 24          // HT + 8 halo
#define RC 24          // WTL + 8 halo
#define PADW 200       // padded image dim (192 + 2*4)

typedef __attribute__((ext_vector_type(8))) short bf16x8;
typedef __attribute__((ext_vector_type(4))) float f32x4;

typedef __attribute__((address_space(1))) const void gvoid;   // global
typedef __attribute__((address_space(3))) void svoid;         // LDS

__device__ __forceinline__ unsigned short f2bf(float f) {
    union { float f; unsigned int u; } v; v.f = f;
    unsigned int r = v.u + 0x7fffu + ((v.u >> 16) & 1u);
    return (unsigned short)(r >> 16);
}

// ============ weight generation (device func, shared by prep + fallback) ====
// Layout (bf16 as ushort): W2g[mt][tap][quad][m][j]  (mt=o>>4, m=o&15, quad=i>>3, j=i&7)
__device__ __forceinline__ void genw_body(int b, int t, int nthr,
                                          const float* __restrict__ wp,
                                          unsigned short* __restrict__ W2g,
                                          float* ws /* shared, nthr/64 floats */) {
    const int o = b >> 5;
    const int i = b & 31;
    float sx = wp[b * 3 + 0], sy = wp[b * 3 + 1], th = wp[b * 3 + 2];
    float rad = th / 180.0f * 3.14159265358979323846f;
    float co = cosf(rad), si = sinf(rad);
    float sx2 = sx * sx, sy2 = sy * sy;
    float a = co * co * sx2 + si * si * sy2;
    float bb = co * si * (sx2 - sy2);
    float d = si * si * sx2 + co * co * sy2;
    float det = a * d - bb * bb;
    float ia = d / det, ib = -bb / det, idd = a / det;

    const int tap = t;
    float e = 0.0f;
    if (tap < 81) {
        float xx = (float)(tap % 9 - 4);
        float yy = (float)(tap / 9 - 4);
        float q = ia * xx * xx + 2.0f * ib * xx * yy + idd * yy * yy;
        e = expf(-0.5f * q);
    }
    float s = e;
    #pragma unroll
    for (int off = 32; off > 0; off >>= 1) s += __shfl_down(s, off);
    if ((t & 63) == 0) ws[t >> 6] = s;
    __syncthreads();
    float total = 0.0f;
    for (int k = 0; k < nthr / 64; k++) total += ws[k];

    if (tap < 81) {
        int mt = o >> 4, m = o & 15, quad = i >> 3, j = i & 7;
        W2g[((((mt * 81 + tap) * 4 + quad) * 16 + m) << 3) + j] = f2bf(e / total);
    }
}

// ============ prep kernel: xpad build + weight gen in one launch ============
// Blocks [0, 10000): xpad granules. gid = ((n*200+pr)*200+pw)*4 + q, 16 B each.
// Granule holds channels q*8..q*8+7 of pixel (pr-4, pw-4), zeros on border.
// Blocks [10000, 11024): weight generation, b = blockIdx.x - 10000.
__global__ void prep_kernel(const float* __restrict__ x, const float* __restrict__ wp,
                            unsigned short* __restrict__ W2g,
                            unsigned short* __restrict__ xpad) {
    __shared__ float ws[4];
    if (blockIdx.x < 10000) {
        int gid = blockIdx.x * 256 + threadIdx.x;      // 0 .. 2,559,999
        int q = gid & 3;
        int pix = gid >> 2;                             // (n*200+pr)*200+pw
        int pw = pix % PADW;
        int rest = pix / PADW;
        int pr = rest % PADW;
        int n = rest / PADW;
        int r = pr - PADI, c = pw - PADI;
        unsigned int d[4] = {0u, 0u, 0u, 0u};
        if ((unsigned)r < (unsigned)H && (unsigned)c < (unsigned)W) {
            const float* p = x + (((size_t)n * CIN + q * 8) * H + r) * W + c;
            #pragma unroll
            for (int k = 0; k < 4; k++) {
                float v0 = p[(size_t)(2 * k) * H * W];
                float v1 = p[(size_t)(2 * k + 1) * H * W];
                d[k] = (unsigned int)f2bf(v0) | ((unsigned int)f2bf(v1) << 16);
            }
        }
        *(uint4*)(xpad + (size_t)gid * 8) = make_uint4(d[0], d[1], d[2], d[3]);
    } else {
        genw_body(blockIdx.x - 10000, threadIdx.x, 256, wp, W2g, ws);
    }
}

// standalone genw for the fallback path
__global__ void genw_kernel(const float* __restrict__ wp, unsigned short* __restrict__ W2g) {
    __shared__ float ws[2];
    genw_body(blockIdx.x, threadIdx.x, 128, wp, W2g, ws);
}

// ============ conv kernel (DMA staging via global_load_lds) =================
// Block: 256 thr = 4 waves; tile 16x16 px, 32 och. Wave w: mt=w&1, rows (w>>1)*8..+8.
// LDS layout [quad][r][w][8ch]: granule g = (quad*RR + r)*RC + w, 16 B each —
// identical to R3's proven layout. Staging: wave `wv` DMAs quad-slab `wv`
// (576 granules = 9 x global_load_lds dwordx4; dest = uniform base + lane*16).
__global__ __launch_bounds__(256, 4) void conv_kernel(
    const unsigned short* __restrict__ xpad, const unsigned short* __restrict__ W2g,
    const float* __restrict__ bias, float* __restrict__ out)
{
    __shared__ __align__(16) unsigned short ldsx[4 * RR * RC * 8];  // 36,864 B

    const int t = threadIdx.x;
    // XCD-contiguous swizzle: 8 classes x 288 tiles (= 2 whole images per class)
    const int bid = (blockIdx.x & 7) * 288 + (blockIdx.x >> 3);
    const int wb = bid % (W / WTL);                 // 0..11
    const int hb = (bid / (W / WTL)) % (H / HT);    // 0..11
    const int n  = bid / ((W / WTL) * (H / HT));    // 0..15
    const int wave = t >> 6;
    const int lane = t & 63;

    // ---- DMA staging: 9 global_load_lds per wave, no VGPR round-trip ----
    // src pixel (pr,pw) = (hb*HT + r, wb*WTL + w) in padded coords; 64 B/pixel.
    {
        const size_t pixbase = ((size_t)n * PADW + hb * HT) * PADW + wb * WTL;
        const unsigned short* srcq = xpad + pixbase * 32 + wave * 8;  // +wave*16B
        #pragma unroll
        for (int k = 0; k < 9; k++) {
            int rem = k * 64 + lane;            // 0..575 within this quad-slab
            int r = rem / RC;
            int w = rem - r * RC;
            const unsigned short* src = srcq + ((size_t)r * PADW + w) * 32;
            char* dst = (char*)ldsx + ((size_t)(wave * 576 + k * 64) * 16);
            __builtin_amdgcn_global_load_lds((gvoid*)src, (svoid*)dst, 16, 0, 0);
        }
    }

    const int l15 = lane & 15;      // A: m-row / B: pixel col / D: col
    const int quad4 = lane >> 4;    // A/B: k-group (8 ch) / D: och-quad
    const int mt = wave & 1;        // och tile (16 och)
    const int rbase = (wave >> 1) * 8;

    const bf16x8* __restrict__ Wp = (const bf16x8*)W2g;

    // preload A-frags for dx=0 (hidden under the DMA drain + barrier)
    bf16x8 A[2][9];
    #pragma unroll
    for (int dy = 0; dy < 9; dy++)
        A[0][dy] = Wp[((mt * 81 + dy * 9 + 0) * 4 + quad4) * 16 + l15];

    __syncthreads();   // drains vmcnt -> DMA complete

    f32x4 acc[8];
    #pragma unroll
    for (int i = 0; i < 8; i++) acc[i] = (f32x4){0.f, 0.f, 0.f, 0.f};

    const unsigned short* bptr = &ldsx[(size_t)(((quad4 * RR + rbase) * RC) + l15) * 8];

    #pragma unroll
    for (int dx = 0; dx < 9; dx++) {
        const int cur = dx & 1, nxt = cur ^ 1;
        if (dx < 8) {
            #pragma unroll
            for (int dy = 0; dy < 9; dy++)
                A[nxt][dy] = Wp[((mt * 81 + dy * 9 + (dx + 1)) * 4 + quad4) * 16 + l15];
        }
        #pragma unroll
        for (int rr = 0; rr < 16; rr++) {           // lds row rel to rbase; out_r = rr - dy
            const bf16x8 bfrag = *(const bf16x8*)&bptr[(size_t)(rr * RC + dx) * 8];
            #pragma unroll
            for (int dy = 0; dy < 9; dy++) {
                const int orr = rr - dy;
                if (orr >= 0 && orr < 8) {
                    acc[orr] = __builtin_amdgcn_mfma_f32_16x16x32_bf16(
                        A[cur][dy], bfrag, acc[orr], 0, 0, 0);
                }
            }
        }
    }

    // ---- epilogue: D layout col = lane&15 (pixel), row = quad4*4 + reg ----
    float* outn = out + (size_t)n * NOUT * H * W;
    float bb[4];
    #pragma unroll
    for (int reg = 0; reg < 4; reg++) bb[reg] = bias[mt * 16 + quad4 * 4 + reg];
    #pragma unroll
    for (int orr = 0; orr < 8; orr++) {
        const int row = hb * HT + rbase + orr;
        const int col = wb * WTL + l15;
        #pragma unroll
        for (int reg = 0; reg < 4; reg++) {
            const int och = mt * 16 + quad4 * 4 + reg;
            outn[((size_t)och * H + row) * W + col] = acc[orr][reg] + bb[reg];
        }
    }
}

// ============ fallback conv (R3 path, reads x directly) =====================
__global__ __launch_bounds__(256, 4) void conv_fb(
    const float* __restrict__ x, const unsigned short* __restrict__ W2g,
    const float* __restrict__ bias, float* __restrict__ out)
{
    __shared__ __align__(16) unsigned short ldsx[4 * RR * RC * 8];

    const int t = threadIdx.x;
    const int bid = (blockIdx.x & 7) * 288 + (blockIdx.x >> 3);
    const int wb = bid % (W / WTL);
    const int hb = (bid / (W / WTL)) % (H / HT);
    const int n  = bid / ((W / WTL) * (H / HT));
    const int row0 = hb * HT - PADI;
    const int col0 = wb * WTL - PADI;
    const float* xn = x + (size_t)n * CIN * H * W;

    float v[9][8];
    #pragma unroll
    for (int it = 0; it < 9; ++it) {
        int idx = it * 256 + t;
        int w = idx % RC;
        int r = (idx / RC) % RR;
        int quad = idx / (RC * RR);
        int row = row0 + r, col = col0 + w;
        #pragma unroll
        for (int k = 0; k < 8; k++) v[it][k] = 0.0f;
        if ((unsigned)row < (unsigned)H && (unsigned)col < (unsigned)W) {
            const float* p = xn + ((size_t)(quad * 8) * H + row) * W + col;
            #pragma unroll
            for (int k = 0; k < 8; k++) v[it][k] = p[(size_t)k * H * W];
        }
    }
    #pragma unroll
    for (int it = 0; it < 9; ++it) {
        int idx = it * 256 + t;
        unsigned int d[4];
        #pragma unroll
        for (int k = 0; k < 4; k++)
            d[k] = (unsigned int)f2bf(v[it][2 * k]) | ((unsigned int)f2bf(v[it][2 * k + 1]) << 16);
        *(uint4*)&ldsx[(size_t)idx * 8] = make_uint4(d[0], d[1], d[2], d[3]);
    }

    const int wave = t >> 6;
    const int lane = t & 63;
    const int l15 = lane & 15;
    const int quad4 = lane >> 4;
    const int mt = wave & 1;
    const int rbase = (wave >> 1) * 8;

    const bf16x8* __restrict__ Wp = (const bf16x8*)W2g;
    bf16x8 A[2][9];
    #pragma unroll
    for (int dy = 0; dy < 9; dy++)
        A[0][dy] = Wp[((mt * 81 + dy * 9 + 0) * 4 + quad4) * 16 + l15];

    __syncthreads();

    f32x4 acc[8];
    #pragma unroll
    for (int i = 0; i < 8; i++) acc[i] = (f32x4){0.f, 0.f, 0.f, 0.f};

    const unsigned short* bptr = &ldsx[(size_t)(((quad4 * RR + rbase) * RC) + l15) * 8];

    #pragma unroll
    for (int dx = 0; dx < 9; dx++) {
        const int cur = dx & 1, nxt = cur ^ 1;
        if (dx < 8) {
            #pragma unroll
            for (int dy = 0; dy < 9; dy++)
                A[nxt][dy] = Wp[((mt * 81 + dy * 9 + (dx + 1)) * 4 + quad4) * 16 + l15];
        }
        #pragma unroll
        for (int rr = 0; rr < 16; rr++) {
            const bf16x8 bfrag = *(const bf16x8*)&bptr[(size_t)(rr * RC + dx) * 8];
            #pragma unroll
            for (int dy = 0; dy < 9; dy++) {
                const int orr = rr - dy;
                if (orr >= 0 && orr < 8) {
                    acc[orr] = __builtin_amdgcn_mfma_f32_16x16x32_bf16(
                        A[cur][dy], bfrag, acc[orr], 0, 0, 0);
                }
            }
        }
    }

    float* outn = out + (size_t)n * NOUT * H * W;
    float bb[4];
    #pragma unroll
    for (int reg = 0; reg < 4; reg++) bb[reg] = bias[mt * 16 + quad4 * 4 + reg];
    #pragma unroll
    for (int orr = 0; orr < 8; orr++) {
        const int row = hb * HT + rbase + orr;
        const int col = wb * WTL + l15;
        #pragma unroll
        for (int reg = 0; reg < 4; reg++) {
            const int och = mt * 16 + quad4 * 4 + reg;
            outn[((size_t)och * H + row) * W + col] = acc[orr][reg] + bb[reg];
        }
    }
}

extern "C" void kernel_launch(void* const* d_in, const int* in_sizes, int n_in,
                              void* d_out, int out_size, void* d_ws, size_t ws_size,
                              hipStream_t stream) {
    const float* x    = (const float*)d_in[0];
    const float* wp   = (const float*)d_in[1];   // (32,32,3)
    const float* bias = (const float*)d_in[2];   // (32,)
    float* out = (float*)d_out;

    const size_t W2G_BYTES  = 165888;                               // 256-aligned
    const size_t XPAD_BYTES = (size_t)NB * PADW * PADW * CIN * 2;   // 40,960,000

    unsigned short* W2g  = (unsigned short*)d_ws;
    const int blocks = NB * (H / HT) * (W / WTL);   // 2304

    if (ws_size >= W2G_BYTES + XPAD_BYTES) {
        unsigned short* xpad = (unsigned short*)((char*)d_ws + W2G_BYTES);
        prep_kernel<<<11024, 256, 0, stream>>>(x, wp, W2g, xpad);
        conv_kernel<<<blocks, 256, 0, stream>>>(xpad, W2g, bias, out);
    } else {
        genw_kernel<<<NOUT * CIN, 128, 0, stream>>>(wp, W2g);
        conv_fb<<<blocks, 256, 0, stream>>>(x, W2g, bias, out);
    }
}